// Round 1
// baseline (188.242 us; speedup 1.0000x reference)
//
#include <hip/hip_runtime.h>

typedef __attribute__((ext_vector_type(8))) short short8;
typedef __attribute__((ext_vector_type(4))) float floatx4;

// Quantize one float to the PACT integer (q - zp) and return its exact bf16 bits.
// |q - zp| <= 256 -> integer is exact in bf16, so plain truncation of the fp32
// bits is exact (low 16 bits are already zero).
__device__ __forceinline__ unsigned short quant_bf16(float x, float cvn, float cv,
                                                     float scale, float zp) {
    float xc = fminf(fmaxf(x, cvn), cv);
    float q  = rintf(xc * scale + zp);   // RNE, matches jnp.round
    float v  = q - zp;                   // integer in [-256, 256]
    return (unsigned short)(__float_as_uint(v) >> 16);
}

// m1: [32][1024][128] fp32 -> qA same layout, bf16 integer values.
__global__ __launch_bounds__(256) void quant_m1_kernel(
        const float* __restrict__ x, unsigned short* __restrict__ q,
        const float* __restrict__ cvp, const float* __restrict__ cvnp, int n4) {
    int i = blockIdx.x * 256 + threadIdx.x;
    if (i >= n4) return;
    float cv = cvp[0], cvn = cvnp[0];
    float scale = 255.0f / (cv - cvn);
    float zp = rintf(-cvn * scale);
    float4 v = ((const float4*)x)[i];
    ushort4 o;
    o.x = quant_bf16(v.x, cvn, cv, scale, zp);
    o.y = quant_bf16(v.y, cvn, cv, scale, zp);
    o.z = quant_bf16(v.z, cvn, cv, scale, zp);
    o.w = quant_bf16(v.w, cvn, cv, scale, zp);
    ((ushort4*)q)[i] = o;
}

// m2: [32][128 d][1024 s] fp32 -> qBt: [32][1024 s][128 d] bf16 integer values
// (transposed so GEMM B-fragments are k-contiguous). LDS-tiled transpose.
__global__ __launch_bounds__(256) void quant_m2t_kernel(
        const float* __restrict__ x, unsigned short* __restrict__ qt,
        const float* __restrict__ cvp, const float* __restrict__ cvnp) {
    __shared__ unsigned short tile[128][129];  // +1 pad breaks bank alignment
    int batch = blockIdx.y;
    int s0 = blockIdx.x * 128;
    const float* xb = x + (size_t)batch * (128 * 1024);
    unsigned short* qb = qt + (size_t)batch * (1024 * 128);
    float cv = cvp[0], cvn = cvnp[0];
    float scale = 255.0f / (cv - cvn);
    float zp = rintf(-cvn * scale);
    int t = threadIdx.x;
    int c4 = t & 31;          // float4 column within the 128-wide s tile
    int dbase = t >> 5;       // 0..7
#pragma unroll
    for (int r = 0; r < 16; ++r) {
        int d = dbase + r * 8;                       // 0..127
        float4 v = *(const float4*)(xb + d * 1024 + s0 + c4 * 4);
        tile[d][c4 * 4 + 0] = quant_bf16(v.x, cvn, cv, scale, zp);
        tile[d][c4 * 4 + 1] = quant_bf16(v.y, cvn, cv, scale, zp);
        tile[d][c4 * 4 + 2] = quant_bf16(v.z, cvn, cv, scale, zp);
        tile[d][c4 * 4 + 3] = quant_bf16(v.w, cvn, cv, scale, zp);
    }
    __syncthreads();
    int k8 = t & 15;          // 16B chunk along d
    int slb = t >> 4;         // 0..15
#pragma unroll
    for (int r = 0; r < 8; ++r) {
        int sl = slb + r * 16;                       // 0..127
        short8 o;
#pragma unroll
        for (int j = 0; j < 8; ++j) o[j] = (short)tile[k8 * 8 + j][sl];
        *(short8*)(qb + (size_t)(s0 + sl) * 128 + k8 * 8) = o;  // coalesced 16B
    }
}

// Batched GEMM: C[b][s][t] = (sum_d qa[s][d]*qbt[t][d]) * inv_scale.
// 128x128 tile per block, 4 waves (2x2), each wave 4x4 MFMA 16x16x32 tiles,
// K=128 fully unrolled. No LDS: both operands are k-contiguous in global, so
// fragments load directly as 16B dwordx4.
__global__ __launch_bounds__(256, 3) void qbmm_kernel(
        const unsigned short* __restrict__ qA, const unsigned short* __restrict__ qBt,
        float* __restrict__ C,
        const float* __restrict__ cv1p, const float* __restrict__ cvn1p,
        const float* __restrict__ cv2p, const float* __restrict__ cvn2p) {
    int batch = blockIdx.z;
    const unsigned short* A  = qA  + (size_t)batch * (1024 * 128);
    const unsigned short* Bt = qBt + (size_t)batch * (1024 * 128);
    float* Cb = C + (size_t)batch * (1024 * 1024);
    int m0 = blockIdx.y * 128, n0 = blockIdx.x * 128;
    int tid = threadIdx.x;
    int lane = tid & 63, w = tid >> 6;
    int wr = w >> 1, wc = w & 1;
    int row16 = lane & 15, quad = lane >> 4;
    int wm = m0 + wr * 64, wn = n0 + wc * 64;

    floatx4 acc[4][4] = {};

    const short8* Ap[4];
    const short8* Bp[4];
#pragma unroll
    for (int i = 0; i < 4; ++i) {
        // A fragment: A[m = wm+i*16+row16][k = quad*8 + j], j contiguous
        Ap[i] = (const short8*)(A  + (size_t)(wm + i * 16 + row16) * 128 + quad * 8);
        // B fragment (from transposed qBt): B[k][n=wn+i*16+row16] = qBt[n][k]
        Bp[i] = (const short8*)(Bt + (size_t)(wn + i * 16 + row16) * 128 + quad * 8);
    }

#pragma unroll
    for (int kk = 0; kk < 4; ++kk) {          // k-step of 32
        short8 a[4], b[4];
#pragma unroll
        for (int i = 0; i < 4; ++i) { a[i] = Ap[i][kk * 4]; b[i] = Bp[i][kk * 4]; }
#pragma unroll
        for (int mi = 0; mi < 4; ++mi)
#pragma unroll
            for (int ni = 0; ni < 4; ++ni)
                acc[mi][ni] = __builtin_amdgcn_mfma_f32_16x16x32_bf16(
                    a[mi], b[ni], acc[mi][ni], 0, 0, 0);
    }

    // inv = 1/(scale1*scale2) = (cv1-cvn1)*(cv2-cvn2)/255^2
    float inv = (cv1p[0] - cvn1p[0]) * (cv2p[0] - cvn2p[0]) * (1.0f / 65025.0f);

#pragma unroll
    for (int mi = 0; mi < 4; ++mi) {
#pragma unroll
        for (int r = 0; r < 4; ++r) {
            int row = wm + mi * 16 + quad * 4 + r;   // C/D: row = quad*4 + reg
            float* crow = Cb + (size_t)row * 1024 + wn + row16;
#pragma unroll
            for (int ni = 0; ni < 4; ++ni)
                crow[ni * 16] = acc[mi][ni][r] * inv;
        }
    }
}

extern "C" void kernel_launch(void* const* d_in, const int* in_sizes, int n_in,
                              void* d_out, int out_size, void* d_ws, size_t ws_size,
                              hipStream_t stream) {
    const float* m1   = (const float*)d_in[0];
    const float* m2   = (const float*)d_in[1];
    const float* cv1  = (const float*)d_in[2];
    const float* cvn1 = (const float*)d_in[3];
    const float* cv2  = (const float*)d_in[4];
    const float* cvn2 = (const float*)d_in[5];
    float* out = (float*)d_out;

    unsigned short* qA  = (unsigned short*)d_ws;   // 4.19M bf16 = 8.39 MB
    unsigned short* qBt = qA + 4194304;            // 8.39 MB, transposed m2

    // m1: 4194304 floats -> 1048576 float4s
    quant_m1_kernel<<<4096, 256, 0, stream>>>(m1, qA, cv1, cvn1, 1048576);
    // m2: 32 batches x (8 column-tiles of 128)
    quant_m2t_kernel<<<dim3(8, 32), 256, 0, stream>>>(m2, qBt, cv2, cvn2);
    // GEMM: 8x8 tiles x 32 batches
    qbmm_kernel<<<dim3(8, 8, 32), 256, 0, stream>>>(qA, qBt, out,
                                                    cv1, cvn1, cv2, cvn2);
}